// Round 4
// baseline (339.438 us; speedup 1.0000x reference)
//
#include <hip/hip_runtime.h>
#include <hip/hip_fp16.h>

#define B_ 2
#define CX 64
#define HH 192
#define WW 192
#define HW (HH*WW)
#define HS 48
#define WS 48
#define HWS (HS*WS)
#define CE 160
#define C4 432
#define DG_ 16
#define COUT_D 128

typedef short bf16x8 __attribute__((ext_vector_type(8)));
typedef _Float16 f16x8 __attribute__((ext_vector_type(8)));
typedef float f32x4 __attribute__((ext_vector_type(4)));
typedef float f32x16 __attribute__((ext_vector_type(16)));
typedef unsigned short u16;

__device__ __forceinline__ unsigned f2bf(float f) {
    unsigned u = __float_as_uint(f);
    return (u + 0x7FFFu + ((u >> 16) & 1u)) >> 16;   // RNE
}
__device__ __forceinline__ float bf2f(u16 h) {
    return __uint_as_float(((unsigned)h) << 16);
}
__device__ __forceinline__ void split_hl(float v, u16& h, u16& l) {
    h = (u16)f2bf(v);
    l = (u16)f2bf(v - bf2f(h));
}
__device__ __forceinline__ float tanh_fast(float v) {
    float e = __expf(2.f * v);
    return 1.f - 2.f * __builtin_amdgcn_rcpf(e + 1.f);
}
__device__ __forceinline__ float sigmoid_fast(float s) {
    return __builtin_amdgcn_rcpf(1.f + __expf(-s));
}

// ---------------- fused prep: zp + wq1 + wq2 + wq3 + wA ----------------
__device__ __forceinline__ void prep_wq_body(const float* __restrict__ w, u16* __restrict__ wq,
                                             int i, int OC, int OCP, int CIN) {
    int ic = i % CIN; int rest = i / CIN;
    int oc = rest % OCP; rest /= OCP;
    int q = rest % 9; int kind = rest / 9;
    float v = (oc < OC) ? w[((size_t)oc * CIN + ic) * 9 + q] : 0.f;
    u16 h, l; split_hl(v, h, l);
    wq[i] = kind ? l : h;
}

__global__ void fused_prep_kernel(const float* __restrict__ w1, const float* __restrict__ w2,
                                  const float* __restrict__ w3, const float* __restrict__ wgt,
                                  float* __restrict__ zp, u16* __restrict__ wq1,
                                  u16* __restrict__ wq2, u16* __restrict__ wq3,
                                  u16* __restrict__ wA) {
    int bid = blockIdx.x, t = threadIdx.x;
    if (bid == 0) { zp[t] = 0.f; return; }
    if (bid < 721)  { prep_wq_body(w1, wq1, (bid - 1) * 256 + t, 64, 64, 160); return; }
    if (bid < 1009) { prep_wq_body(w2, wq2, (bid - 721) * 256 + t, 64, 64, 64); return; }
    if (bid < 1297) { prep_wq_body(w3, wq3, (bid - 1009) * 256 + t, 64, 64, 64); return; }
    // wA fp16: [o][g*80 + tap*8 + c], taps 9..9(pad)=0
    int i = (bid - 1297) * 256 + t;                  // 128*1280 = 640*256
    int o = i / 1280, col = i - o * 1280;
    int g = col / 80, r = col - g * 80;
    int tap = r >> 3, c = r & 7;
    float v = (tap < 9) ? wgt[(size_t)o * 1152 + (g * 8 + c) * 9 + tap] : 0.f;
    wA[i] = __half_as_ushort(__float2half_rn(v));
}

// ---------------- wq4 prep (separate: aliases pool_t, runs after conv1) ----------------
__global__ void prep_wq4_kernel(const float* __restrict__ w, u16* __restrict__ wq) {
    prep_wq_body(w, wq, blockIdx.x * 256 + threadIdx.x, 432, 448, 64);
}

// ---------------- fused: x/addf -> NHWC fp16 xg ; avgpool4+concat -> pool_t ----------------
__global__ void fused_trans_pool_kernel(const float* __restrict__ x, const float* __restrict__ flow,
                                        const float* __restrict__ addf,
                                        u16* __restrict__ xg, u16* __restrict__ pt) {
    int bid = blockIdx.x, t = threadIdx.x;
    if (bid < 4608) {
        int i = bid * 256 + t;                       // 2*16*36864
        int p = i % HW;
        int g = (i / HW) % DG_;
        int b = i / (HW * DG_);
        const float* xb = x    + ((size_t)(b * CX + g * 4)) * HW + p;
        const float* ab = addf + ((size_t)(b * CX + g * 4)) * HW + p;
        __half2 h[4];
        h[0].x = __float2half_rn(xb[0]);      h[0].y = __float2half_rn(xb[HW]);
        h[1].x = __float2half_rn(xb[2 * HW]); h[1].y = __float2half_rn(xb[3 * HW]);
        h[2].x = __float2half_rn(ab[0]);      h[2].y = __float2half_rn(ab[HW]);
        h[3].x = __float2half_rn(ab[2 * HW]); h[3].y = __float2half_rn(ab[3 * HW]);
        *reinterpret_cast<uint4*>(&xg[(size_t)i * 8]) = *reinterpret_cast<uint4*>(h);
    } else {
        int i = (bid - 4608) * 256 + t;              // 737280
        int xs = i % WS, ys = (i / WS) % HS, c = (i / HWS) % CE, b = i / (HWS * CE);
        const float* src;
        if (c < 64)      src = x    + (size_t)(b * 64 + c) * HW;
        else if (c < 96) src = flow + (size_t)(b * 32 + (c - 64)) * HW;
        else             src = addf + (size_t)(b * 64 + (c - 96)) * HW;
        const float4* s4 = reinterpret_cast<const float4*>(src + (ys * 4) * WW + xs * 4);
        float sum = 0.f;
#pragma unroll
        for (int r = 0; r < 4; ++r) {
            float4 v = s4[r * (WW / 4)];
            sum += v.x + v.y + v.z + v.w;
        }
        float v = sum * (1.f / 16.f);
        u16 h, l; split_hl(v, h, l);
        size_t base = ((size_t)(b * HWS + ys * WS + xs) * 2) * CE + c;
        pt[base] = h; pt[base + CE] = l;
    }
}

// ---------------- K-split MFMA 3x3 conv (64 oc), 8 waves: 4 ocgrp x 2 khalf ----------------
template<int CIN, int KB0, int KBT, bool LRELU>
__global__ __launch_bounds__(512) void conv_ks(const u16* __restrict__ in_t,
                                               const u16* __restrict__ wq,
                                               const float* __restrict__ bias,
                                               u16* __restrict__ out_t,
                                               const float* __restrict__ zp) {
    __shared__ float red[1024];                      // [ocgrp][r][l4][l15]
    const int t = threadIdx.x;
    const int w = t >> 6;
    const int ocgrp = w & 3, kh = w >> 2;
    const int l15 = t & 15, l4 = (t >> 4) & 3;
    const int tile = blockIdx.x;
    const int ty0 = (tile / 12) * 4, tx0 = (tile % 12) * 4;
    const int b = blockIdx.z;
    const int ocb = ocgrp * 16;
    const int py = ty0 + (l15 >> 2), pxx = tx0 + (l15 & 3);
    f32x4 ahh = {0,0,0,0}, ahl = {0,0,0,0}, alh = {0,0,0,0};
    const u16* inb = in_t + (size_t)b * (HWS * 2 * CIN);
    const u16* zp16 = (const u16*)zp;

#define CONV_BODY(KS, KE)                                                             \
    _Pragma("unroll")                                                                 \
    for (int q = 0; q < 9; ++q) {                                                     \
        int sy = py + q / 3 - 1, sx = pxx + q % 3 - 1;                                \
        bool valid = ((unsigned)sy < 48u) && ((unsigned)sx < 48u);                    \
        const u16* bh = valid ? inb + ((size_t)(sy * 48 + sx) * 2) * CIN : zp16;      \
        const u16* bl = valid ? inb + ((size_t)(sy * 48 + sx) * 2 + 1) * CIN : zp16;  \
        const u16* wh = wq + ((size_t)q * 64 + ocb + l15) * CIN + l4 * 8;             \
        const u16* wl = wq + ((size_t)(9 + q) * 64 + ocb + l15) * CIN + l4 * 8;       \
        _Pragma("unroll")                                                             \
        for (int kb = (KS); kb < (KE); ++kb) {                                        \
            bf16x8 Ah = *reinterpret_cast<const bf16x8*>(wh + kb * 32);               \
            bf16x8 Al = *reinterpret_cast<const bf16x8*>(wl + kb * 32);               \
            bf16x8 Bh = *reinterpret_cast<const bf16x8*>(bh + kb * 32 + l4 * 8);      \
            bf16x8 Bl = *reinterpret_cast<const bf16x8*>(bl + kb * 32 + l4 * 8);      \
            ahh = __builtin_amdgcn_mfma_f32_16x16x32_bf16(Ah, Bh, ahh, 0, 0, 0);      \
            ahl = __builtin_amdgcn_mfma_f32_16x16x32_bf16(Ah, Bl, ahl, 0, 0, 0);      \
            alh = __builtin_amdgcn_mfma_f32_16x16x32_bf16(Al, Bh, alh, 0, 0, 0);      \
        }                                                                             \
    }
    if (kh == 0) { CONV_BODY(0, KB0) } else { CONV_BODY(KB0, KBT) }
#undef CONV_BODY

    float vsum[4];
#pragma unroll
    for (int r = 0; r < 4; ++r) vsum[r] = ahh[r] + ahl[r] + alh[r];
    if (kh) {
#pragma unroll
        for (int r = 0; r < 4; ++r) red[((ocgrp * 4 + r) * 4 + l4) * 16 + l15] = vsum[r];
    }
    __syncthreads();
    if (!kh) {
#pragma unroll
        for (int r = 0; r < 4; ++r) {
            int oc = ocb + l4 * 4 + r;
            float v = vsum[r] + red[((ocgrp * 4 + r) * 4 + l4) * 16 + l15] + bias[oc];
            if (LRELU) v = (v >= 0.f) ? v : 0.2f * v;
            u16 h, l; split_hl(v, h, l);
            size_t base = ((size_t)(b * HWS + py * 48 + pxx) * 2) * 64 + oc;
            out_t[base] = h; out_t[base + 64] = l;
        }
    }
}

// ---------------- MFMA 3x3 conv (conv4: 432 oc, f32 out), 4 waves ----------------
template<int CIN, int OC, int OCP, bool LRELU>
__global__ __launch_bounds__(256) void conv_mfma(const u16* __restrict__ in_t,
                                                 const u16* __restrict__ wq,
                                                 const float* __restrict__ bias,
                                                 float* __restrict__ out_f,
                                                 const float* __restrict__ zp) {
    const int t = threadIdx.x;
    const int wv = __builtin_amdgcn_readfirstlane(t >> 6);
    const int l15 = t & 15, l4 = (t >> 4) & 3;
    const int tile = blockIdx.x;
    const int ty0 = (tile / 12) * 4, tx0 = (tile % 12) * 4;
    const int ocb = blockIdx.y * 64 + wv * 16;
    const int b = blockIdx.z;
    const int py = ty0 + (l15 >> 2), pxx = tx0 + (l15 & 3);
    f32x4 ahh = {0,0,0,0}, ahl = {0,0,0,0}, alh = {0,0,0,0};
    const u16* inb = in_t + (size_t)b * (HWS * 2 * CIN);
    const u16* zp16 = (const u16*)zp;
#pragma unroll
    for (int q = 0; q < 9; ++q) {
        int sy = py + q / 3 - 1, sx = pxx + q % 3 - 1;
        bool valid = ((unsigned)sy < 48u) && ((unsigned)sx < 48u);
        const u16* bh = valid ? inb + ((size_t)(sy * 48 + sx) * 2) * CIN : zp16;
        const u16* bl = valid ? inb + ((size_t)(sy * 48 + sx) * 2 + 1) * CIN : zp16;
        const u16* wh = wq + ((size_t)q * OCP + ocb + l15) * CIN + l4 * 8;
        const u16* wl = wq + ((size_t)(9 + q) * OCP + ocb + l15) * CIN + l4 * 8;
#pragma unroll
        for (int kb = 0; kb < CIN / 32; ++kb) {
            bf16x8 Ah = *reinterpret_cast<const bf16x8*>(wh + kb * 32);
            bf16x8 Al = *reinterpret_cast<const bf16x8*>(wl + kb * 32);
            bf16x8 Bh = *reinterpret_cast<const bf16x8*>(bh + kb * 32 + l4 * 8);
            bf16x8 Bl = *reinterpret_cast<const bf16x8*>(bl + kb * 32 + l4 * 8);
            ahh = __builtin_amdgcn_mfma_f32_16x16x32_bf16(Ah, Bh, ahh, 0, 0, 0);
            ahl = __builtin_amdgcn_mfma_f32_16x16x32_bf16(Ah, Bl, ahl, 0, 0, 0);
            alh = __builtin_amdgcn_mfma_f32_16x16x32_bf16(Al, Bh, alh, 0, 0, 0);
        }
    }
#pragma unroll
    for (int r = 0; r < 4; ++r) {
        int oc = ocb + l4 * 4 + r;
        float v = ahh[r] + ahl[r] + alh[r] + ((oc < OC) ? bias[oc] : 0.f);
        if (LRELU) v = (v >= 0.f) ? v : 0.2f * v;
        if (oc < OC) out_f[((size_t)(b * OC + oc)) * HWS + py * 48 + pxx] = v;
    }
}

// ---------------- deform v4: per-lane register B-frags, 32x32x16 f16 MFMA ----------------
// block = 4 waves, tile = 8 rows x 16 cols; wave = 32 px x 128 oc
__global__ __launch_bounds__(256) void deform_mfma(
    const u16* __restrict__ xg, const float* __restrict__ flow,
    const float* __restrict__ a4, const u16* __restrict__ wAg,
    const float* __restrict__ bias, float* __restrict__ out)
{
    __shared__ u16 awq[2][128 * 88];                 // A weights [oc][80k pad 88], fp16 bits
    const int t = threadIdx.x;
    const int bx = blockIdx.x, b = blockIdx.y;
    const int ty0 = (bx / 12) * 8, tx0 = (bx % 12) * 16;
    const int lane = t & 63;
    const int w = t >> 6;
    const int l31 = lane & 31, l5h = lane >> 5;
    const int py = ty0 + (w & 1) * 4 + (l31 >> 3);
    const int px = tx0 + (w >> 1) * 8 + (l31 & 7);
    const int pyx = py * WW + px;

    // hoisted 4x-resize cells + weights (px-only, group/tap-independent)
    float ysf = fminf(fmaxf((py + 0.5f) * 0.25f - 0.5f, 0.f), 47.f);
    float xsf = fminf(fmaxf((px + 0.5f) * 0.25f - 0.5f, 0.f), 47.f);
    int iy0 = (int)ysf, ix0 = (int)xsf;
    float fy = ysf - (float)iy0, fx = xsf - (float)ix0;
    int iy1 = min(iy0 + 1, 47), ix1 = min(ix0 + 1, 47);
    int c00 = iy0 * 48 + ix0, c01 = iy0 * 48 + ix1;
    int c10 = iy1 * 48 + ix0, c11 = iy1 * 48 + ix1;
    float r00 = (1.f - fy) * (1.f - fx), r01 = (1.f - fy) * fx;
    float r10 = fy * (1.f - fx), r11 = fy * fx;

    f32x16 acc[4];
    f32x16 z16 = {};
    acc[0] = z16; acc[1] = z16; acc[2] = z16; acc[3] = z16;

    const float* a4b = a4 + (size_t)b * C4 * HWS;
    const float* flb = flow + (size_t)b * 32 * HW;
    const u16* xgb0 = xg + (size_t)b * DG_ * HW * 8;

#define STAGE_A(gg, bb) do {                                                  \
    _Pragma("unroll")                                                         \
    for (int j = 0; j < 5; ++j) {                                             \
        int u = t * 5 + j; int row = u / 10, un = u - row * 10;               \
        uint4 tmp = *reinterpret_cast<const uint4*>(                          \
            &wAg[(size_t)row * 1280 + (gg) * 80 + un * 8]);                   \
        *reinterpret_cast<uint4*>(&awq[bb][row * 88 + un * 8]) = tmp;         \
    }                                                                         \
} while (0)

    STAGE_A(0, 0);

    for (int g = 0; g < DG_; ++g) {
        const int buf = g & 1;
        if (g < 15) STAGE_A(g + 1, buf ^ 1);
        float fdy = flb[(size_t)(2 * g + 1) * HW + pyx];
        float fdx = flb[(size_t)(2 * g) * HW + pyx];
        const u16* xgb = xgb0 + (size_t)g * HW * 8;
        f16x8 Bf[5];
#pragma unroll
        for (int kb = 0; kb < 5; ++kb) {
            int kt = kb * 2 + l5h;
            if (kt < 9) {
                const float* pd = a4b + (size_t)(g * 18 + 2 * kt) * HWS;
                const float* pm = a4b + (size_t)(288 + g * 9 + kt) * HWS;
                float sdy = pd[c00] * r00 + pd[c01] * r01 + pd[c10] * r10 + pd[c11] * r11;
                float sdx = pd[c00 + HWS] * r00 + pd[c01 + HWS] * r01
                          + pd[c10 + HWS] * r10 + pd[c11 + HWS] * r11;
                float sm  = pm[c00] * r00 + pm[c01] * r01 + pm[c10] * r10 + pm[c11] * r11;
                float dyv = 5.f * tanh_fast(sdy) + fdy;
                float dxv = 5.f * tanh_fast(sdx) + fdx;
                float m = sigmoid_fast(sm);
                float fpy = (float)(py + kt / 3 - 1) + dyv;
                float fpx = (float)(px + kt % 3 - 1) + dxv;
                float y0f = floorf(fpy), x0f = floorf(fpx);
                int gy0 = (int)y0f, gx0 = (int)x0f;
                int gy1 = gy0 + 1, gx1 = gx0 + 1;
                float wy = fpy - y0f, wx = fpx - x0f;
                bool by0 = (unsigned)gy0 < (unsigned)HH, by1 = (unsigned)gy1 < (unsigned)HH;
                bool bx0v = (unsigned)gx0 < (unsigned)WW, bx1v = (unsigned)gx1 < (unsigned)WW;
                int y0c = min(max(gy0, 0), HH - 1), y1c = min(max(gy1, 0), HH - 1);
                int x0c = min(max(gx0, 0), WW - 1), x1c = min(max(gx1, 0), WW - 1);
                float w00 = (by0 && bx0v) ? (1.f - wy) * (1.f - wx) * m : 0.f;
                float w01 = (by0 && bx1v) ? (1.f - wy) * wx * m : 0.f;
                float w10 = (by1 && bx0v) ? wy * (1.f - wx) * m : 0.f;
                float w11 = (by1 && bx1v) ? wy * wx * m : 0.f;
                uint4 v00 = *reinterpret_cast<const uint4*>(&xgb[(size_t)(y0c * WW + x0c) * 8]);
                uint4 v01 = *reinterpret_cast<const uint4*>(&xgb[(size_t)(y0c * WW + x1c) * 8]);
                uint4 v10 = *reinterpret_cast<const uint4*>(&xgb[(size_t)(y1c * WW + x0c) * 8]);
                uint4 v11 = *reinterpret_cast<const uint4*>(&xgb[(size_t)(y1c * WW + x1c) * 8]);
                const __half2* h00 = reinterpret_cast<const __half2*>(&v00);
                const __half2* h01 = reinterpret_cast<const __half2*>(&v01);
                const __half2* h10 = reinterpret_cast<const __half2*>(&v10);
                const __half2* h11 = reinterpret_cast<const __half2*>(&v11);
                __half hw00 = __float2half_rn(w00), hw01 = __float2half_rn(w01);
                __half hw10 = __float2half_rn(w10), hw11 = __float2half_rn(w11);
                __half2 W00{hw00, hw00}, W01{hw01, hw01}, W10{hw10, hw10}, W11{hw11, hw11};
                union { __half2 h2[4]; f16x8 v; } u;
#pragma unroll
                for (int cc = 0; cc < 4; ++cc)
                    u.h2[cc] = __hfma2(h00[cc], W00, __hfma2(h01[cc], W01,
                               __hfma2(h10[cc], W10, __hmul2(h11[cc], W11))));
                Bf[kb] = u.v;
            } else {
                f16x8 z = {};
                Bf[kb] = z;
            }
        }
        __syncthreads();                             // awq[buf] ready (staged last iter)
#pragma unroll
        for (int kb = 0; kb < 5; ++kb) {
#pragma unroll
            for (int mf = 0; mf < 4; ++mf) {
                f16x8 a = *reinterpret_cast<const f16x8*>(
                    &awq[buf][(mf * 32 + l31) * 88 + (kb * 2 + l5h) * 8]);
                acc[mf] = __builtin_amdgcn_mfma_f32_32x32x16_f16(a, Bf[kb], acc[mf], 0, 0, 0);
            }
        }
        __syncthreads();                             // protect awq[buf^1] WAR for next stage
    }
#undef STAGE_A
    // epilogue: C col=lane&31 (pixel), row=(reg&3)+8*(reg>>2)+4*(lane>>5)
#pragma unroll
    for (int mf = 0; mf < 4; ++mf) {
#pragma unroll
        for (int r = 0; r < 16; ++r) {
            int row = (r & 3) + 8 * (r >> 2) + 4 * l5h;
            int o = mf * 32 + row;
            out[((size_t)(b * COUT_D + o)) * HW + pyx] = acc[mf][r] + bias[o];
        }
    }
}

extern "C" void kernel_launch(void* const* d_in, const int* in_sizes, int n_in,
                              void* d_out, int out_size, void* d_ws, size_t ws_size,
                              hipStream_t stream) {
    const float* x    = (const float*)d_in[0];
    const float* flow = (const float*)d_in[1];
    const float* addf = (const float*)d_in[2];
    const float* w1   = (const float*)d_in[3];
    const float* b1   = (const float*)d_in[4];
    const float* w2   = (const float*)d_in[5];
    const float* b2   = (const float*)d_in[6];
    const float* w3   = (const float*)d_in[7];
    const float* b3   = (const float*)d_in[8];
    const float* w4   = (const float*)d_in[9];
    const float* b4   = (const float*)d_in[10];
    const float* wgt  = (const float*)d_in[11];
    const float* bias = (const float*)d_in[12];
    float* out = (float*)d_out;
    float* ws = (float*)d_ws;

    float* zp    = ws;                               // 256 f32
    u16*  pool_t = (u16*)(ws + 256);                 // 1,474,560 u16
    u16*  c1     = pool_t + 1474560;                 // 589,824 u16
    u16*  c2     = c1 + 589824;                      // 589,824 u16
    u16*  c3     = c1;                               // alias (c1 dead after conv2)
    float* a4    = (float*)(c2 + 589824);            // 1,990,656 f32
    u16*  wq1    = (u16*)(a4 + 1990656);             // 184,320 u16
    u16*  wq2    = wq1 + 184320;                     // 73,728
    u16*  wq3    = wq2 + 73728;                      // 73,728
    u16*  wA     = wq3 + 73728;                      // 163,840 (fp16)
    u16*  xg     = wA + 163840;                      // 9,437,184 (fp16)
    u16*  wq4    = pool_t;                           // alias (pool_t dead after conv1)

    fused_prep_kernel      <<<1937, 256, 0, stream>>>(w1, w2, w3, wgt, zp, wq1, wq2, wq3, wA);
    fused_trans_pool_kernel<<<7488, 256, 0, stream>>>(x, flow, addf, xg, pool_t);

    conv_ks<160, 3, 5, true><<<dim3(144, 1, 2), 512, 0, stream>>>(pool_t, wq1, b1, c1, zp);
    prep_wq4_kernel        <<<2016, 256, 0, stream>>>(w4, wq4);
    conv_ks<64, 1, 2, true><<<dim3(144, 1, 2), 512, 0, stream>>>(c1, wq2, b2, c2, zp);
    conv_ks<64, 1, 2, true><<<dim3(144, 1, 2), 512, 0, stream>>>(c2, wq3, b3, c3, zp);
    conv_mfma<64, 432, 448, false><<<dim3(144, 7, 2), 256, 0, stream>>>(c3, wq4, b4, a4, zp);

    deform_mfma<<<dim3(288, 2), 256, 0, stream>>>(xg, flow, a4, wA, bias, out);
}

// Round 5
// 286.357 us; speedup vs baseline: 1.1854x; 1.1854x over previous
//
#include <hip/hip_runtime.h>
#include <hip/hip_fp16.h>

#define B_ 2
#define CX 64
#define HH 192
#define WW 192
#define HW (HH*WW)
#define HS 48
#define WS 48
#define HWS (HS*WS)
#define CE 160
#define C4 432
#define DG_ 16
#define COUT_D 128

typedef short bf16x8 __attribute__((ext_vector_type(8)));
typedef _Float16 f16x8 __attribute__((ext_vector_type(8)));
typedef float f32x4 __attribute__((ext_vector_type(4)));
typedef unsigned short u16;

__device__ __forceinline__ unsigned f2bf(float f) {
    unsigned u = __float_as_uint(f);
    return (u + 0x7FFFu + ((u >> 16) & 1u)) >> 16;   // RNE
}
__device__ __forceinline__ float bf2f(u16 h) {
    return __uint_as_float(((unsigned)h) << 16);
}
__device__ __forceinline__ void split_hl(float v, u16& h, u16& l) {
    h = (u16)f2bf(v);
    l = (u16)f2bf(v - bf2f(h));
}
__device__ __forceinline__ float tanh_fast(float v) {
    float e = __expf(2.f * v);
    return 1.f - 2.f * __builtin_amdgcn_rcpf(e + 1.f);
}
__device__ __forceinline__ float sigmoid_fast(float s) {
    return __builtin_amdgcn_rcpf(1.f + __expf(-s));
}

// ---------------- fused prep: zp + wq1..wq4 + wA ----------------
__device__ __forceinline__ void prep_wq_body(const float* __restrict__ w, u16* __restrict__ wq,
                                             int i, int OC, int OCP, int CIN) {
    int ic = i % CIN; int rest = i / CIN;
    int oc = rest % OCP; rest /= OCP;
    int q = rest % 9; int kind = rest / 9;
    float v = (oc < OC) ? w[((size_t)oc * CIN + ic) * 9 + q] : 0.f;
    u16 h, l; split_hl(v, h, l);
    wq[i] = kind ? l : h;
}

__global__ void fused_prep_kernel(const float* __restrict__ w1, const float* __restrict__ w2,
                                  const float* __restrict__ w3, const float* __restrict__ w4,
                                  const float* __restrict__ wgt,
                                  float* __restrict__ zp, u16* __restrict__ wq1,
                                  u16* __restrict__ wq2, u16* __restrict__ wq3,
                                  u16* __restrict__ wq4, u16* __restrict__ wA) {
    int bid = blockIdx.x, t = threadIdx.x;
    if (bid == 0) { zp[t] = 0.f; return; }
    if (bid < 721)  { prep_wq_body(w1, wq1, (bid - 1) * 256 + t, 64, 64, 160); return; }
    if (bid < 1009) { prep_wq_body(w2, wq2, (bid - 721) * 256 + t, 64, 64, 64); return; }
    if (bid < 1297) { prep_wq_body(w3, wq3, (bid - 1009) * 256 + t, 64, 64, 64); return; }
    if (bid < 3313) { prep_wq_body(w4, wq4, (bid - 1297) * 256 + t, 432, 448, 64); return; }
    // wA fp16: [o][g*96 + tap*8 + c], taps 9..11 = 0
    int i = (bid - 3313) * 256 + t;                  // 128*1536 = 768*256
    int o = i / 1536, col = i - o * 1536;
    int g = col / 96, r = col - g * 96;
    int tap = r >> 3, c = r & 7;
    float v = (tap < 9) ? wgt[(size_t)o * 1152 + (g * 8 + c) * 9 + tap] : 0.f;
    wA[i] = __half_as_ushort(__float2half_rn(v));
}

// ---------------- fused: x/addf -> NHWC fp16 xg ; avgpool4+concat -> pool_t ----------------
__global__ void fused_trans_pool_kernel(const float* __restrict__ x, const float* __restrict__ flow,
                                        const float* __restrict__ addf,
                                        u16* __restrict__ xg, u16* __restrict__ pt) {
    int bid = blockIdx.x, t = threadIdx.x;
    if (bid < 4608) {
        int i = bid * 256 + t;                       // 2*16*36864
        int p = i % HW;
        int g = (i / HW) % DG_;
        int b = i / (HW * DG_);
        const float* xb = x    + ((size_t)(b * CX + g * 4)) * HW + p;
        const float* ab = addf + ((size_t)(b * CX + g * 4)) * HW + p;
        __half2 h[4];
        h[0].x = __float2half_rn(xb[0]);      h[0].y = __float2half_rn(xb[HW]);
        h[1].x = __float2half_rn(xb[2 * HW]); h[1].y = __float2half_rn(xb[3 * HW]);
        h[2].x = __float2half_rn(ab[0]);      h[2].y = __float2half_rn(ab[HW]);
        h[3].x = __float2half_rn(ab[2 * HW]); h[3].y = __float2half_rn(ab[3 * HW]);
        *reinterpret_cast<uint4*>(&xg[(size_t)i * 8]) = *reinterpret_cast<uint4*>(h);
    } else {
        int i = (bid - 4608) * 256 + t;              // 737280
        int xs = i % WS, ys = (i / WS) % HS, c = (i / HWS) % CE, b = i / (HWS * CE);
        const float* src;
        if (c < 64)      src = x    + (size_t)(b * 64 + c) * HW;
        else if (c < 96) src = flow + (size_t)(b * 32 + (c - 64)) * HW;
        else             src = addf + (size_t)(b * 64 + (c - 96)) * HW;
        const float4* s4 = reinterpret_cast<const float4*>(src + (ys * 4) * WW + xs * 4);
        float sum = 0.f;
#pragma unroll
        for (int r = 0; r < 4; ++r) {
            float4 v = s4[r * (WW / 4)];
            sum += v.x + v.y + v.z + v.w;
        }
        float v = sum * (1.f / 16.f);
        u16 h, l; split_hl(v, h, l);
        size_t base = ((size_t)(b * HWS + ys * WS + xs) * 2) * CE + c;
        pt[base] = h; pt[base + CE] = l;
    }
}

// ---------------- 4-way K-split MFMA 3x3 conv (64 oc), 16 waves: 4 ocgrp x 4 ksplit ----------------
template<int CIN, int U0, int U1, int U2, int UT, bool LRELU>
__global__ __launch_bounds__(1024) void conv_ks(const u16* __restrict__ in_t,
                                                const u16* __restrict__ wq,
                                                const float* __restrict__ bias,
                                                u16* __restrict__ out_t,
                                                const float* __restrict__ zp) {
    __shared__ float red[3 * 4 * 256];               // [ks-1][ocgrp][r*64+lane]
    const int t = threadIdx.x;
    const int w = t >> 6;
    const int ocgrp = w & 3, ks = w >> 2;
    const int lane = t & 63;
    const int l15 = t & 15, l4 = (t >> 4) & 3;
    const int tile = blockIdx.x;
    const int ty0 = (tile / 12) * 4, tx0 = (tile % 12) * 4;
    const int b = blockIdx.z;
    const int ocb = ocgrp * 16;
    const int py = ty0 + (l15 >> 2), pxx = tx0 + (l15 & 3);
    f32x4 ahh = {0,0,0,0}, ahl = {0,0,0,0}, alh = {0,0,0,0};
    const u16* inb = in_t + (size_t)b * (HWS * 2 * CIN);
    const u16* zp16 = (const u16*)zp;
    constexpr int KB = CIN / 32;

#define CONV_BODY(US, UE)                                                             \
    _Pragma("unroll")                                                                 \
    for (int u = (US); u < (UE); ++u) {                                               \
        const int q = u / KB, kb = u % KB;                                            \
        int sy = py + q / 3 - 1, sx = pxx + q % 3 - 1;                                \
        bool valid = ((unsigned)sy < 48u) && ((unsigned)sx < 48u);                    \
        const u16* bh = valid ? inb + ((size_t)(sy * 48 + sx) * 2) * CIN : zp16;      \
        const u16* bl = valid ? inb + ((size_t)(sy * 48 + sx) * 2 + 1) * CIN : zp16;  \
        const u16* wh = wq + ((size_t)q * 64 + ocb + l15) * CIN + l4 * 8 + kb * 32;   \
        const u16* wl = wh + (size_t)9 * 64 * CIN;                                    \
        bf16x8 Ah = *reinterpret_cast<const bf16x8*>(wh);                             \
        bf16x8 Al = *reinterpret_cast<const bf16x8*>(wl);                             \
        bf16x8 Bh = *reinterpret_cast<const bf16x8*>(bh + kb * 32 + l4 * 8);          \
        bf16x8 Bl = *reinterpret_cast<const bf16x8*>(bl + kb * 32 + l4 * 8);          \
        ahh = __builtin_amdgcn_mfma_f32_16x16x32_bf16(Ah, Bh, ahh, 0, 0, 0);          \
        ahl = __builtin_amdgcn_mfma_f32_16x16x32_bf16(Ah, Bl, ahl, 0, 0, 0);          \
        alh = __builtin_amdgcn_mfma_f32_16x16x32_bf16(Al, Bh, alh, 0, 0, 0);          \
    }
    if (ks == 0)      { CONV_BODY(0,  U0) }
    else if (ks == 1) { CONV_BODY(U0, U1) }
    else if (ks == 2) { CONV_BODY(U1, U2) }
    else              { CONV_BODY(U2, UT) }
#undef CONV_BODY

    float vsum[4];
#pragma unroll
    for (int r = 0; r < 4; ++r) vsum[r] = ahh[r] + ahl[r] + alh[r];
    if (ks) {
#pragma unroll
        for (int r = 0; r < 4; ++r)
            red[((ks - 1) * 4 + ocgrp) * 256 + r * 64 + lane] = vsum[r];
    }
    __syncthreads();
    if (!ks) {
#pragma unroll
        for (int r = 0; r < 4; ++r) {
#pragma unroll
            for (int j = 0; j < 3; ++j)
                vsum[r] += red[(j * 4 + ocgrp) * 256 + r * 64 + lane];
            int oc = ocb + l4 * 4 + r;
            float v = vsum[r] + bias[oc];
            if (LRELU) v = (v >= 0.f) ? v : 0.2f * v;
            u16 h, l; split_hl(v, h, l);
            size_t base = ((size_t)(b * HWS + py * 48 + pxx) * 2) * 64 + oc;
            out_t[base] = h; out_t[base + 64] = l;
        }
    }
}

// ---------------- MFMA 3x3 conv (conv4: 432 oc, f32 out), 4 waves ----------------
template<int CIN, int OC, int OCP, bool LRELU>
__global__ __launch_bounds__(256) void conv_mfma(const u16* __restrict__ in_t,
                                                 const u16* __restrict__ wq,
                                                 const float* __restrict__ bias,
                                                 float* __restrict__ out_f,
                                                 const float* __restrict__ zp) {
    const int t = threadIdx.x;
    const int wv = __builtin_amdgcn_readfirstlane(t >> 6);
    const int l15 = t & 15, l4 = (t >> 4) & 3;
    const int tile = blockIdx.x;
    const int ty0 = (tile / 12) * 4, tx0 = (tile % 12) * 4;
    const int ocb = blockIdx.y * 64 + wv * 16;
    const int b = blockIdx.z;
    const int py = ty0 + (l15 >> 2), pxx = tx0 + (l15 & 3);
    f32x4 ahh = {0,0,0,0}, ahl = {0,0,0,0}, alh = {0,0,0,0};
    const u16* inb = in_t + (size_t)b * (HWS * 2 * CIN);
    const u16* zp16 = (const u16*)zp;
#pragma unroll
    for (int q = 0; q < 9; ++q) {
        int sy = py + q / 3 - 1, sx = pxx + q % 3 - 1;
        bool valid = ((unsigned)sy < 48u) && ((unsigned)sx < 48u);
        const u16* bh = valid ? inb + ((size_t)(sy * 48 + sx) * 2) * CIN : zp16;
        const u16* bl = valid ? inb + ((size_t)(sy * 48 + sx) * 2 + 1) * CIN : zp16;
        const u16* wh = wq + ((size_t)q * OCP + ocb + l15) * CIN + l4 * 8;
        const u16* wl = wq + ((size_t)(9 + q) * OCP + ocb + l15) * CIN + l4 * 8;
#pragma unroll
        for (int kb = 0; kb < CIN / 32; ++kb) {
            bf16x8 Ah = *reinterpret_cast<const bf16x8*>(wh + kb * 32);
            bf16x8 Al = *reinterpret_cast<const bf16x8*>(wl + kb * 32);
            bf16x8 Bh = *reinterpret_cast<const bf16x8*>(bh + kb * 32 + l4 * 8);
            bf16x8 Bl = *reinterpret_cast<const bf16x8*>(bl + kb * 32 + l4 * 8);
            ahh = __builtin_amdgcn_mfma_f32_16x16x32_bf16(Ah, Bh, ahh, 0, 0, 0);
            ahl = __builtin_amdgcn_mfma_f32_16x16x32_bf16(Ah, Bl, ahl, 0, 0, 0);
            alh = __builtin_amdgcn_mfma_f32_16x16x32_bf16(Al, Bh, alh, 0, 0, 0);
        }
    }
#pragma unroll
    for (int r = 0; r < 4; ++r) {
        int oc = ocb + l4 * 4 + r;
        float v = ahh[r] + ahl[r] + alh[r] + ((oc < OC) ? bias[oc] : 0.f);
        if (LRELU) v = (v >= 0.f) ? v : 0.2f * v;
        if (oc < OC) out_f[((size_t)(b * OC + oc)) * HWS + py * 48 + pxx] = v;
    }
}

// ---------------- deform v5: R3 skeleton, 8 waves (16oc each), fp16, hoisted resize ----------------
__global__ __launch_bounds__(512) void deform_mfma(
    const u16* __restrict__ xg, const float* __restrict__ flow,
    const float* __restrict__ a4, const u16* __restrict__ wA,
    const float* __restrict__ bias, float* __restrict__ out)
{
    __shared__ u16 val[2][64 * 104];                 // fp16 [pixel][ck pad 96->104]
    __shared__ float a4t[2][27 * 16];
    __shared__ float flds[2][128];
    __shared__ float rw[4][64];
    __shared__ int rb[64];
    const int t = threadIdx.x;
    const int tile = blockIdx.x, b = blockIdx.y;
    const int ty0 = (tile / 24) * 8, tx0 = (tile % 24) * 8;
    const int lane = t & 63;
    const int og = __builtin_amdgcn_readfirstlane(t >> 6);
    const int l15 = lane & 15, l4 = lane >> 4;
    const int ys0 = (ty0 >> 2) - 1, xs0 = (tx0 >> 2) - 1;

    f32x4 acc[4];
#pragma unroll
    for (int n = 0; n < 4; ++n) acc[n] = (f32x4){0.f, 0.f, 0.f, 0.f};

    // p-wise resize cells/weights (group/tap independent)
    if (t < 64) {
        int p = t;
        int y = ty0 + (p >> 3), xx = tx0 + (p & 7);
        float ysf = fminf(fmaxf((y + 0.5f) * 0.25f - 0.5f, 0.f), 47.f);
        float xsf = fminf(fmaxf((xx + 0.5f) * 0.25f - 0.5f, 0.f), 47.f);
        int ry0 = (int)ysf, rx0 = (int)xsf;
        float fy = ysf - (float)ry0, fx = xsf - (float)rx0;
        rb[p] = (ry0 - ys0) * 4 + (rx0 - xs0);
        rw[0][p] = (1.f - fy) * (1.f - fx);
        rw[1][p] = (1.f - fy) * fx;
        rw[2][p] = fy * (1.f - fx);
        rw[3][p] = fy * fx;
    }
    // zero K-pad units (cols 72..95) of both val buffers
    if (t < 384) {
        int bb = (t >= 192) ? 1 : 0; int j = t - bb * 192;
        int row = j / 3, un = 9 + j % 3;
        *reinterpret_cast<uint4*>(&val[bb][row * 104 + un * 8]) = make_uint4(0, 0, 0, 0);
    }

    const float* a4b = a4 + (size_t)b * C4 * HWS;
    const float* flb = flow + (size_t)b * 32 * HW;
    const u16* xgb0 = xg + (size_t)b * DG_ * HW * 8;

#define STAGE(gg, bb) do {                                                          \
    const int gk = (gg);                                                            \
    if (t < 432) {                                                                  \
        int ch = t >> 4, idx = t & 15;                                              \
        int gy = min(max(ys0 + (idx >> 2), 0), 47);                                 \
        int gx = min(max(xs0 + (idx & 3), 0), 47);                                  \
        int a4ch = (ch < 18) ? (gk * 18 + ch) : (288 + gk * 9 + (ch - 18));         \
        a4t[bb][t] = a4b[(size_t)a4ch * HWS + gy * 48 + gx];                        \
    }                                                                               \
    if (t < 128) {                                                                  \
        int comp = t >> 6, p = t & 63;                                              \
        int y = ty0 + (p >> 3), xx = tx0 + (p & 7);                                 \
        flds[bb][t] = flb[(size_t)(2 * gk + 1 - comp) * HW + y * WW + xx];          \
    }                                                                               \
} while (0)

#define PH12(gg, bb) do {                                                           \
    const u16* xgb = xgb0 + (size_t)(gg) * HW * 8;                                  \
    for (int i = t; i < 576; i += 512) {                                            \
        int k = i >> 6, p = i & 63;                                                 \
        int y = ty0 + (p >> 3), xx = tx0 + (p & 7);                                 \
        int base = rb[p];                                                           \
        float r00 = rw[0][p], r01 = rw[1][p], r10 = rw[2][p], r11 = rw[3][p];       \
        const float* A = &a4t[bb][0];                                               \
        float sdy = A[(2*k)*16+base]*r00 + A[(2*k)*16+base+1]*r01                   \
                  + A[(2*k)*16+base+4]*r10 + A[(2*k)*16+base+5]*r11;                \
        float sdx = A[(2*k+1)*16+base]*r00 + A[(2*k+1)*16+base+1]*r01               \
                  + A[(2*k+1)*16+base+4]*r10 + A[(2*k+1)*16+base+5]*r11;            \
        float sm  = A[(18+k)*16+base]*r00 + A[(18+k)*16+base+1]*r01                 \
                  + A[(18+k)*16+base+4]*r10 + A[(18+k)*16+base+5]*r11;              \
        float dyv = 5.f * tanh_fast(sdy) + flds[bb][p];                             \
        float dxv = 5.f * tanh_fast(sdx) + flds[bb][64 + p];                        \
        float m = sigmoid_fast(sm);                                                 \
        float fpy = (float)(y + (k / 3) - 1) + dyv;                                 \
        float fpx = (float)(xx + (k % 3) - 1) + dxv;                                \
        float y0f = floorf(fpy), x0f = floorf(fpx);                                 \
        int gy0 = (int)y0f, gx0 = (int)x0f;                                         \
        int gy1 = gy0 + 1, gx1 = gx0 + 1;                                           \
        float wy = fpy - y0f, wx = fpx - x0f;                                       \
        bool by0 = (unsigned)gy0 < (unsigned)HH, by1 = (unsigned)gy1 < (unsigned)HH;\
        bool bx0 = (unsigned)gx0 < (unsigned)WW, bx1 = (unsigned)gx1 < (unsigned)WW;\
        int y0c = min(max(gy0, 0), HH - 1), y1c = min(max(gy1, 0), HH - 1);         \
        int x0c = min(max(gx0, 0), WW - 1), x1c = min(max(gx1, 0), WW - 1);         \
        float w00 = (by0 && bx0) ? (1.f - wy) * (1.f - wx) * m : 0.f;               \
        float w01 = (by0 && bx1) ? (1.f - wy) * wx * m : 0.f;                       \
        float w10 = (by1 && bx0) ? wy * (1.f - wx) * m : 0.f;                       \
        float w11 = (by1 && bx1) ? wy * wx * m : 0.f;                               \
        uint4 v00 = *reinterpret_cast<const uint4*>(&xgb[(size_t)(y0c * WW + x0c) * 8]); \
        uint4 v01 = *reinterpret_cast<const uint4*>(&xgb[(size_t)(y0c * WW + x1c) * 8]); \
        uint4 v10 = *reinterpret_cast<const uint4*>(&xgb[(size_t)(y1c * WW + x0c) * 8]); \
        uint4 v11 = *reinterpret_cast<const uint4*>(&xgb[(size_t)(y1c * WW + x1c) * 8]); \
        const __half2* h00 = reinterpret_cast<const __half2*>(&v00);                \
        const __half2* h01 = reinterpret_cast<const __half2*>(&v01);                \
        const __half2* h10 = reinterpret_cast<const __half2*>(&v10);                \
        const __half2* h11 = reinterpret_cast<const __half2*>(&v11);                \
        __half hw00 = __float2half_rn(w00), hw01 = __float2half_rn(w01);            \
        __half hw10 = __float2half_rn(w10), hw11 = __float2half_rn(w11);            \
        __half2 W00{hw00, hw00}, W01{hw01, hw01}, W10{hw10, hw10}, W11{hw11, hw11}; \
        union { __half2 h2[4]; uint4 u4; } uu;                                      \
        _Pragma("unroll")                                                           \
        for (int cc = 0; cc < 4; ++cc)                                              \
            uu.h2[cc] = __hfma2(h00[cc], W00, __hfma2(h01[cc], W01,                 \
                        __hfma2(h10[cc], W10, __hmul2(h11[cc], W11))));             \
        *reinterpret_cast<uint4*>(&val[bb][p * 104 + k * 8]) = uu.u4;               \
    }                                                                               \
} while (0)

    STAGE(0, 0);
    __syncthreads();

    for (int g = 0; g < DG_; ++g) {
        const int buf = g & 1;
        if (g < 15) STAGE(g + 1, buf ^ 1);
        PH12(g, buf);
        __syncthreads();
        const u16* wg = wA + (size_t)(og * 16) * 1536 + g * 96;
#pragma unroll
        for (int kb = 0; kb < 3; ++kb) {
            f16x8 a = *reinterpret_cast<const f16x8*>(wg + (size_t)l15 * 1536 + kb * 32 + l4 * 8);
#pragma unroll
            for (int nf = 0; nf < 4; ++nf) {
                int row = nf * 16 + l15;
                f16x8 bfrag = *reinterpret_cast<const f16x8*>(
                    &val[buf][row * 104 + kb * 32 + l4 * 8]);
                acc[nf] = __builtin_amdgcn_mfma_f32_16x16x32_f16(a, bfrag, acc[nf], 0, 0, 0);
            }
        }
    }
#undef STAGE
#undef PH12
    // epilogue: D col=lane&15 (pixel), row=(lane>>4)*4+reg (oc within 16)
#pragma unroll
    for (int nf = 0; nf < 4; ++nf) {
        int pix = nf * 16 + l15;
        int py = ty0 + (pix >> 3), px = tx0 + (pix & 7);
#pragma unroll
        for (int r = 0; r < 4; ++r) {
            int o = og * 16 + l4 * 4 + r;
            out[((size_t)(b * COUT_D + o) * HH + py) * WW + px] = acc[nf][r] + bias[o];
        }
    }
}

extern "C" void kernel_launch(void* const* d_in, const int* in_sizes, int n_in,
                              void* d_out, int out_size, void* d_ws, size_t ws_size,
                              hipStream_t stream) {
    const float* x    = (const float*)d_in[0];
    const float* flow = (const float*)d_in[1];
    const float* addf = (const float*)d_in[2];
    const float* w1   = (const float*)d_in[3];
    const float* b1   = (const float*)d_in[4];
    const float* w2   = (const float*)d_in[5];
    const float* b2   = (const float*)d_in[6];
    const float* w3   = (const float*)d_in[7];
    const float* b3   = (const float*)d_in[8];
    const float* w4   = (const float*)d_in[9];
    const float* b4   = (const float*)d_in[10];
    const float* wgt  = (const float*)d_in[11];
    const float* bias = (const float*)d_in[12];
    float* out = (float*)d_out;
    float* ws = (float*)d_ws;

    float* zp    = ws;                               // 256 f32
    u16*  pool_t = (u16*)(ws + 256);                 // 1,474,560 u16
    u16*  c1     = pool_t + 1474560;                 // 589,824 u16
    u16*  c2     = c1 + 589824;                      // 589,824 u16
    u16*  c3     = c1;                               // alias (c1 dead after conv2)
    float* a4    = (float*)(c2 + 589824);            // 1,990,656 f32
    u16*  wq1    = (u16*)(a4 + 1990656);             // 184,320 u16
    u16*  wq2    = wq1 + 184320;                     // 73,728
    u16*  wq3    = wq2 + 73728;                      // 73,728
    u16*  wq4    = wq3 + 73728;                      // 516,096
    u16*  wA     = wq4 + 516096;                     // 196,608 (fp16)
    u16*  xg     = wA + 196608;                      // 9,437,184 (fp16)

    fused_prep_kernel      <<<4081, 256, 0, stream>>>(w1, w2, w3, w4, wgt, zp, wq1, wq2, wq3, wq4, wA);
    fused_trans_pool_kernel<<<7488, 256, 0, stream>>>(x, flow, addf, xg, pool_t);

    conv_ks<160, 12, 23, 34, 45, true><<<dim3(144, 1, 2), 1024, 0, stream>>>(pool_t, wq1, b1, c1, zp);
    conv_ks<64,  5,  10, 14, 18, true><<<dim3(144, 1, 2), 1024, 0, stream>>>(c1, wq2, b2, c2, zp);
    conv_ks<64,  5,  10, 14, 18, true><<<dim3(144, 1, 2), 1024, 0, stream>>>(c2, wq3, b3, c3, zp);
    conv_mfma<64, 432, 448, false><<<dim3(144, 7, 2), 256, 0, stream>>>(c3, wq4, b4, a4, zp);

    deform_mfma<<<dim3(576, 2), 512, 0, stream>>>(xg, flow, a4, wA, bias, out);
}

// Round 9
// 279.714 us; speedup vs baseline: 1.2135x; 1.0237x over previous
//
#include <hip/hip_runtime.h>
#include <hip/hip_fp16.h>

#define B_ 2
#define CX 64
#define HH 192
#define WW 192
#define HW (HH*WW)
#define HS 48
#define WS 48
#define HWS (HS*WS)
#define CE 160
#define C4 432
#define DG_ 16
#define COUT_D 128

typedef short bf16x8 __attribute__((ext_vector_type(8)));
typedef _Float16 f16x8 __attribute__((ext_vector_type(8)));
typedef float f32x4 __attribute__((ext_vector_type(4)));
typedef unsigned short u16;

__device__ __forceinline__ unsigned f2bf(float f) {
    unsigned u = __float_as_uint(f);
    return (u + 0x7FFFu + ((u >> 16) & 1u)) >> 16;   // RNE
}
__device__ __forceinline__ float bf2f(u16 h) {
    return __uint_as_float(((unsigned)h) << 16);
}
__device__ __forceinline__ void split_hl(float v, u16& h, u16& l) {
    h = (u16)f2bf(v);
    l = (u16)f2bf(v - bf2f(h));
}
__device__ __forceinline__ float tanh_fast(float v) {
    float e = __expf(2.f * v);
    return 1.f - 2.f * __builtin_amdgcn_rcpf(e + 1.f);
}
__device__ __forceinline__ float sigmoid_fast(float s) {
    return __builtin_amdgcn_rcpf(1.f + __expf(-s));
}

// ---------------- fused prep: zp + wq1..wq4 + wA ----------------
__device__ __forceinline__ void prep_wq_body(const float* __restrict__ w, u16* __restrict__ wq,
                                             int i, int OC, int OCP, int CIN) {
    int ic = i % CIN; int rest = i / CIN;
    int oc = rest % OCP; rest /= OCP;
    int q = rest % 9; int kind = rest / 9;
    float v = (oc < OC) ? w[((size_t)oc * CIN + ic) * 9 + q] : 0.f;
    u16 h, l; split_hl(v, h, l);
    wq[i] = kind ? l : h;
}

__global__ void fused_prep_kernel(const float* __restrict__ w1, const float* __restrict__ w2,
                                  const float* __restrict__ w3, const float* __restrict__ w4,
                                  const float* __restrict__ wgt,
                                  float* __restrict__ zp, u16* __restrict__ wq1,
                                  u16* __restrict__ wq2, u16* __restrict__ wq3,
                                  u16* __restrict__ wq4, u16* __restrict__ wA) {
    int bid = blockIdx.x, t = threadIdx.x;
    if (bid == 0) { zp[t] = 0.f; return; }
    if (bid < 721)  { prep_wq_body(w1, wq1, (bid - 1) * 256 + t, 64, 64, 160); return; }
    if (bid < 1009) { prep_wq_body(w2, wq2, (bid - 721) * 256 + t, 64, 64, 64); return; }
    if (bid < 1297) { prep_wq_body(w3, wq3, (bid - 1009) * 256 + t, 64, 64, 64); return; }
    if (bid < 3313) { prep_wq_body(w4, wq4, (bid - 1297) * 256 + t, 432, 448, 64); return; }
    // wA fp16: [o][g*96 + tap*8 + c], taps 9..11 = 0
    int i = (bid - 3313) * 256 + t;                  // 128*1536 = 768*256
    int o = i / 1536, col = i - o * 1536;
    int g = col / 96, r = col - g * 96;
    int tap = r >> 3, c = r & 7;
    float v = (tap < 9) ? wgt[(size_t)o * 1152 + (g * 8 + c) * 9 + tap] : 0.f;
    wA[i] = __half_as_ushort(__float2half_rn(v));
}

// ---------------- fused: x/addf -> NHWC fp16 xg ; avgpool4+concat -> pool_t ----------------
__global__ void fused_trans_pool_kernel(const float* __restrict__ x, const float* __restrict__ flow,
                                        const float* __restrict__ addf,
                                        u16* __restrict__ xg, u16* __restrict__ pt) {
    int bid = blockIdx.x, t = threadIdx.x;
    if (bid < 4608) {
        int i = bid * 256 + t;                       // 2*16*36864
        int p = i % HW;
        int g = (i / HW) % DG_;
        int b = i / (HW * DG_);
        const float* xb = x    + ((size_t)(b * CX + g * 4)) * HW + p;
        const float* ab = addf + ((size_t)(b * CX + g * 4)) * HW + p;
        __half2 h[4];
        h[0].x = __float2half_rn(xb[0]);      h[0].y = __float2half_rn(xb[HW]);
        h[1].x = __float2half_rn(xb[2 * HW]); h[1].y = __float2half_rn(xb[3 * HW]);
        h[2].x = __float2half_rn(ab[0]);      h[2].y = __float2half_rn(ab[HW]);
        h[3].x = __float2half_rn(ab[2 * HW]); h[3].y = __float2half_rn(ab[3 * HW]);
        *reinterpret_cast<uint4*>(&xg[(size_t)i * 8]) = *reinterpret_cast<uint4*>(h);
    } else {
        int i = (bid - 4608) * 256 + t;              // 737280
        int xs = i % WS, ys = (i / WS) % HS, c = (i / HWS) % CE, b = i / (HWS * CE);
        const float* src;
        if (c < 64)      src = x    + (size_t)(b * 64 + c) * HW;
        else if (c < 96) src = flow + (size_t)(b * 32 + (c - 64)) * HW;
        else             src = addf + (size_t)(b * 64 + (c - 96)) * HW;
        const float4* s4 = reinterpret_cast<const float4*>(src + (ys * 4) * WW + xs * 4);
        float sum = 0.f;
#pragma unroll
        for (int r = 0; r < 4; ++r) {
            float4 v = s4[r * (WW / 4)];
            sum += v.x + v.y + v.z + v.w;
        }
        float v = sum * (1.f / 16.f);
        u16 h, l; split_hl(v, h, l);
        size_t base = ((size_t)(b * HWS + ys * WS + xs) * 2) * CE + c;
        pt[base] = h; pt[base + CE] = l;
    }
}

// ---------------- 4-way K-split MFMA 3x3 conv (64 oc), 16 waves: 4 ocgrp x 4 ksplit ----------------
template<int CIN, int U0, int U1, int U2, int UT, bool LRELU>
__global__ __launch_bounds__(1024) void conv_ks(const u16* __restrict__ in_t,
                                                const u16* __restrict__ wq,
                                                const float* __restrict__ bias,
                                                u16* __restrict__ out_t,
                                                const float* __restrict__ zp) {
    __shared__ float red[3 * 4 * 256];               // [ks-1][ocgrp][r*64+lane]
    const int t = threadIdx.x;
    const int w = t >> 6;
    const int ocgrp = w & 3, ks = w >> 2;
    const int lane = t & 63;
    const int l15 = t & 15, l4 = (t >> 4) & 3;
    const int tile = blockIdx.x;
    const int ty0 = (tile / 12) * 4, tx0 = (tile % 12) * 4;
    const int b = blockIdx.z;
    const int ocb = ocgrp * 16;
    const int py = ty0 + (l15 >> 2), pxx = tx0 + (l15 & 3);
    f32x4 ahh = {0,0,0,0}, ahl = {0,0,0,0}, alh = {0,0,0,0};
    const u16* inb = in_t + (size_t)b * (HWS * 2 * CIN);
    const u16* zp16 = (const u16*)zp;
    constexpr int KB = CIN / 32;

#define CONV_BODY(US, UE)                                                             \
    _Pragma("unroll")                                                                 \
    for (int u = (US); u < (UE); ++u) {                                               \
        const int q = u / KB, kb = u % KB;                                            \
        int sy = py + q / 3 - 1, sx = pxx + q % 3 - 1;                                \
        bool valid = ((unsigned)sy < 48u) && ((unsigned)sx < 48u);                    \
        const u16* bh = valid ? inb + ((size_t)(sy * 48 + sx) * 2) * CIN : zp16;      \
        const u16* bl = valid ? inb + ((size_t)(sy * 48 + sx) * 2 + 1) * CIN : zp16;  \
        const u16* wh = wq + ((size_t)q * 64 + ocb + l15) * CIN + l4 * 8 + kb * 32;   \
        const u16* wl = wh + (size_t)9 * 64 * CIN;                                    \
        bf16x8 Ah = *reinterpret_cast<const bf16x8*>(wh);                             \
        bf16x8 Al = *reinterpret_cast<const bf16x8*>(wl);                             \
        bf16x8 Bh = *reinterpret_cast<const bf16x8*>(bh + kb * 32 + l4 * 8);          \
        bf16x8 Bl = *reinterpret_cast<const bf16x8*>(bl + kb * 32 + l4 * 8);          \
        ahh = __builtin_amdgcn_mfma_f32_16x16x32_bf16(Ah, Bh, ahh, 0, 0, 0);          \
        ahl = __builtin_amdgcn_mfma_f32_16x16x32_bf16(Ah, Bl, ahl, 0, 0, 0);          \
        alh = __builtin_amdgcn_mfma_f32_16x16x32_bf16(Al, Bh, alh, 0, 0, 0);          \
    }
    if (ks == 0)      { CONV_BODY(0,  U0) }
    else if (ks == 1) { CONV_BODY(U0, U1) }
    else if (ks == 2) { CONV_BODY(U1, U2) }
    else              { CONV_BODY(U2, UT) }
#undef CONV_BODY

    float vsum[4];
#pragma unroll
    for (int r = 0; r < 4; ++r) vsum[r] = ahh[r] + ahl[r] + alh[r];
    if (ks) {
#pragma unroll
        for (int r = 0; r < 4; ++r)
            red[((ks - 1) * 4 + ocgrp) * 256 + r * 64 + lane] = vsum[r];
    }
    __syncthreads();
    if (!ks) {
#pragma unroll
        for (int r = 0; r < 4; ++r) {
#pragma unroll
            for (int j = 0; j < 3; ++j)
                vsum[r] += red[(j * 4 + ocgrp) * 256 + r * 64 + lane];
            int oc = ocb + l4 * 4 + r;
            float v = vsum[r] + bias[oc];
            if (LRELU) v = (v >= 0.f) ? v : 0.2f * v;
            u16 h, l; split_hl(v, h, l);
            size_t base = ((size_t)(b * HWS + py * 48 + pxx) * 2) * 64 + oc;
            out_t[base] = h; out_t[base + 64] = l;
        }
    }
}

// ---------------- MFMA 3x3 conv (conv4: 432 oc, f32 out), 4 waves ----------------
template<int CIN, int OC, int OCP, bool LRELU>
__global__ __launch_bounds__(256) void conv_mfma(const u16* __restrict__ in_t,
                                                 const u16* __restrict__ wq,
                                                 const float* __restrict__ bias,
                                                 float* __restrict__ out_f,
                                                 const float* __restrict__ zp) {
    const int t = threadIdx.x;
    const int wv = __builtin_amdgcn_readfirstlane(t >> 6);
    const int l15 = t & 15, l4 = (t >> 4) & 3;
    const int tile = blockIdx.x;
    const int ty0 = (tile / 12) * 4, tx0 = (tile % 12) * 4;
    const int ocb = blockIdx.y * 64 + wv * 16;
    const int b = blockIdx.z;
    const int py = ty0 + (l15 >> 2), pxx = tx0 + (l15 & 3);
    f32x4 ahh = {0,0,0,0}, ahl = {0,0,0,0}, alh = {0,0,0,0};
    const u16* inb = in_t + (size_t)b * (HWS * 2 * CIN);
    const u16* zp16 = (const u16*)zp;
#pragma unroll
    for (int q = 0; q < 9; ++q) {
        int sy = py + q / 3 - 1, sx = pxx + q % 3 - 1;
        bool valid = ((unsigned)sy < 48u) && ((unsigned)sx < 48u);
        const u16* bh = valid ? inb + ((size_t)(sy * 48 + sx) * 2) * CIN : zp16;
        const u16* bl = valid ? inb + ((size_t)(sy * 48 + sx) * 2 + 1) * CIN : zp16;
        const u16* wh = wq + ((size_t)q * OCP + ocb + l15) * CIN + l4 * 8;
        const u16* wl = wq + ((size_t)(9 + q) * OCP + ocb + l15) * CIN + l4 * 8;
#pragma unroll
        for (int kb = 0; kb < CIN / 32; ++kb) {
            bf16x8 Ah = *reinterpret_cast<const bf16x8*>(wh + kb * 32);
            bf16x8 Al = *reinterpret_cast<const bf16x8*>(wl + kb * 32);
            bf16x8 Bh = *reinterpret_cast<const bf16x8*>(bh + kb * 32 + l4 * 8);
            bf16x8 Bl = *reinterpret_cast<const bf16x8*>(bl + kb * 32 + l4 * 8);
            ahh = __builtin_amdgcn_mfma_f32_16x16x32_bf16(Ah, Bh, ahh, 0, 0, 0);
            ahl = __builtin_amdgcn_mfma_f32_16x16x32_bf16(Ah, Bl, ahl, 0, 0, 0);
            alh = __builtin_amdgcn_mfma_f32_16x16x32_bf16(Al, Bh, alh, 0, 0, 0);
        }
    }
#pragma unroll
    for (int r = 0; r < 4; ++r) {
        int oc = ocb + l4 * 4 + r;
        float v = ahh[r] + ahl[r] + alh[r] + ((oc < OC) ? bias[oc] : 0.f);
        if (LRELU) v = (v >= 0.f) ? v : 0.2f * v;
        if (oc < OC) out_f[((size_t)(b * OC + oc)) * HWS + py * 48 + pxx] = v;
    }
}

// ---------------- deform v9: EXACT R5 (passing) structure + setprio + XCD tile swizzle ----------------
__global__ __launch_bounds__(512) void deform_mfma(
    const u16* __restrict__ xg, const float* __restrict__ flow,
    const float* __restrict__ a4, const u16* __restrict__ wA,
    const float* __restrict__ bias, float* __restrict__ out)
{
    __shared__ u16 val[2][64 * 104];                 // fp16 [pixel][ck pad 96->104]
    __shared__ float a4t[2][27 * 16];
    __shared__ float flds[2][128];
    __shared__ float rw[4][64];
    __shared__ int rb[64];
    const int t = threadIdx.x;
    // XCD-aware swizzle: 576 = 8 * 72 -> each XCD gets a contiguous 3-row tile band
    const int traw = blockIdx.x;
    const int tile = (traw & 7) * 72 + (traw >> 3);
    const int b = blockIdx.y;
    const int ty0 = (tile / 24) * 8, tx0 = (tile % 24) * 8;
    const int lane = t & 63;
    const int og = __builtin_amdgcn_readfirstlane(t >> 6);
    const int l15 = lane & 15, l4 = lane >> 4;
    const int ys0 = (ty0 >> 2) - 1, xs0 = (tx0 >> 2) - 1;

    f32x4 acc[4];
#pragma unroll
    for (int n = 0; n < 4; ++n) acc[n] = (f32x4){0.f, 0.f, 0.f, 0.f};

    // p-wise resize cells/weights (group/tap independent)
    if (t < 64) {
        int p = t;
        int y = ty0 + (p >> 3), xx = tx0 + (p & 7);
        float ysf = fminf(fmaxf((y + 0.5f) * 0.25f - 0.5f, 0.f), 47.f);
        float xsf = fminf(fmaxf((xx + 0.5f) * 0.25f - 0.5f, 0.f), 47.f);
        int ry0 = (int)ysf, rx0 = (int)xsf;
        float fy = ysf - (float)ry0, fx = xsf - (float)rx0;
        rb[p] = (ry0 - ys0) * 4 + (rx0 - xs0);
        rw[0][p] = (1.f - fy) * (1.f - fx);
        rw[1][p] = (1.f - fy) * fx;
        rw[2][p] = fy * (1.f - fx);
        rw[3][p] = fy * fx;
    }
    // zero K-pad units (cols 72..95) of both val buffers
    if (t < 384) {
        int bb = (t >= 192) ? 1 : 0; int j = t - bb * 192;
        int row = j / 3, un = 9 + j % 3;
        *reinterpret_cast<uint4*>(&val[bb][row * 104 + un * 8]) = make_uint4(0, 0, 0, 0);
    }

    const float* a4b = a4 + (size_t)b * C4 * HWS;
    const float* flb = flow + (size_t)b * 32 * HW;
    const u16* xgb0 = xg + (size_t)b * DG_ * HW * 8;

#define STAGE(gg, bb) do {                                                          \
    const int gk = (gg);                                                            \
    if (t < 432) {                                                                  \
        int ch = t >> 4, idx = t & 15;                                              \
        int gy = min(max(ys0 + (idx >> 2), 0), 47);                                 \
        int gx = min(max(xs0 + (idx & 3), 0), 47);                                  \
        int a4ch = (ch < 18) ? (gk * 18 + ch) : (288 + gk * 9 + (ch - 18));         \
        a4t[bb][t] = a4b[(size_t)a4ch * HWS + gy * 48 + gx];                        \
    }                                                                               \
    if (t < 128) {                                                                  \
        int comp = t >> 6, p = t & 63;                                              \
        int y = ty0 + (p >> 3), xx = tx0 + (p & 7);                                 \
        flds[bb][t] = flb[(size_t)(2 * gk + 1 - comp) * HW + y * WW + xx];          \
    }                                                                               \
} while (0)

#define PH12(gg, bb) do {                                                           \
    const u16* xgb = xgb0 + (size_t)(gg) * HW * 8;                                  \
    for (int i = t; i < 576; i += 512) {                                            \
        int k = i >> 6, p = i & 63;                                                 \
        int y = ty0 + (p >> 3), xx = tx0 + (p & 7);                                 \
        int base = rb[p];                                                           \
        float r00 = rw[0][p], r01 = rw[1][p], r10 = rw[2][p], r11 = rw[3][p];       \
        const float* A = &a4t[bb][0];                                               \
        float sdy = A[(2*k)*16+base]*r00 + A[(2*k)*16+base+1]*r01                   \
                  + A[(2*k)*16+base+4]*r10 + A[(2*k)*16+base+5]*r11;                \
        float sdx = A[(2*k+1)*16+base]*r00 + A[(2*k+1)*16+base+1]*r01               \
                  + A[(2*k+1)*16+base+4]*r10 + A[(2*k+1)*16+base+5]*r11;            \
        float sm  = A[(18+k)*16+base]*r00 + A[(18+k)*16+base+1]*r01                 \
                  + A[(18+k)*16+base+4]*r10 + A[(18+k)*16+base+5]*r11;              \
        float dyv = 5.f * tanh_fast(sdy) + flds[bb][p];                             \
        float dxv = 5.f * tanh_fast(sdx) + flds[bb][64 + p];                        \
        float m = sigmoid_fast(sm);                                                 \
        float fpy = (float)(y + (k / 3) - 1) + dyv;                                 \
        float fpx = (float)(xx + (k % 3) - 1) + dxv;                                \
        float y0f = floorf(fpy), x0f = floorf(fpx);                                 \
        int gy0 = (int)y0f, gx0 = (int)x0f;                                         \
        int gy1 = gy0 + 1, gx1 = gx0 + 1;                                           \
        float wy = fpy - y0f, wx = fpx - x0f;                                       \
        bool by0 = (unsigned)gy0 < (unsigned)HH, by1 = (unsigned)gy1 < (unsigned)HH;\
        bool bx0 = (unsigned)gx0 < (unsigned)WW, bx1 = (unsigned)gx1 < (unsigned)WW;\
        int y0c = min(max(gy0, 0), HH - 1), y1c = min(max(gy1, 0), HH - 1);         \
        int x0c = min(max(gx0, 0), WW - 1), x1c = min(max(gx1, 0), WW - 1);         \
        float w00 = (by0 && bx0) ? (1.f - wy) * (1.f - wx) * m : 0.f;               \
        float w01 = (by0 && bx1) ? (1.f - wy) * wx * m : 0.f;                       \
        float w10 = (by1 && bx0) ? wy * (1.f - wx) * m : 0.f;                       \
        float w11 = (by1 && bx1) ? wy * wx * m : 0.f;                               \
        uint4 v00 = *reinterpret_cast<const uint4*>(&xgb[(size_t)(y0c * WW + x0c) * 8]); \
        uint4 v01 = *reinterpret_cast<const uint4*>(&xgb[(size_t)(y0c * WW + x1c) * 8]); \
        uint4 v10 = *reinterpret_cast<const uint4*>(&xgb[(size_t)(y1c * WW + x0c) * 8]); \
        uint4 v11 = *reinterpret_cast<const uint4*>(&xgb[(size_t)(y1c * WW + x1c) * 8]); \
        const __half2* h00 = reinterpret_cast<const __half2*>(&v00);                \
        const __half2* h01 = reinterpret_cast<const __half2*>(&v01);                \
        const __half2* h10 = reinterpret_cast<const __half2*>(&v10);                \
        const __half2* h11 = reinterpret_cast<const __half2*>(&v11);                \
        __half hw00 = __float2half_rn(w00), hw01 = __float2half_rn(w01);            \
        __half hw10 = __float2half_rn(w10), hw11 = __float2half_rn(w11);            \
        __half2 W00{hw00, hw00}, W01{hw01, hw01}, W10{hw10, hw10}, W11{hw11, hw11}; \
        union { __half2 h2[4]; uint4 u4; } uu;                                      \
        _Pragma("unroll")                                                           \
        for (int cc = 0; cc < 4; ++cc)                                              \
            uu.h2[cc] = __hfma2(h00[cc], W00, __hfma2(h01[cc], W01,                 \
                        __hfma2(h10[cc], W10, __hmul2(h11[cc], W11))));             \
        *reinterpret_cast<uint4*>(&val[bb][p * 104 + k * 8]) = uu.u4;               \
    }                                                                               \
} while (0)

    STAGE(0, 0);
    __syncthreads();

    for (int g = 0; g < DG_; ++g) {
        const int buf = g & 1;
        if (g < 15) STAGE(g + 1, buf ^ 1);
        PH12(g, buf);
        __syncthreads();
        const u16* wg = wA + (size_t)(og * 16) * 1536 + g * 96;
        __builtin_amdgcn_s_setprio(1);
#pragma unroll
        for (int kb = 0; kb < 3; ++kb) {
            f16x8 a = *reinterpret_cast<const f16x8*>(wg + (size_t)l15 * 1536 + kb * 32 + l4 * 8);
#pragma unroll
            for (int nf = 0; nf < 4; ++nf) {
                int row = nf * 16 + l15;
                f16x8 bfrag = *reinterpret_cast<const f16x8*>(
                    &val[buf][row * 104 + kb * 32 + l4 * 8]);
                acc[nf] = __builtin_amdgcn_mfma_f32_16x16x32_f16(a, bfrag, acc[nf], 0, 0, 0);
            }
        }
        __builtin_amdgcn_s_setprio(0);
    }
#undef STAGE
#undef PH12
    // epilogue: D col=lane&15 (pixel), row=(lane>>4)*4+reg (oc within 16)
#pragma unroll
    for (int nf = 0; nf < 4; ++nf) {
        int pix = nf * 16 + l15;
        int py = ty0 + (pix >> 3), px = tx0 + (pix & 7);
#pragma unroll
        for (int r = 0; r < 4; ++r) {
            int o = og * 16 + l4 * 4 + r;
            out[((size_t)(b * COUT_D + o) * HH + py) * WW + px] = acc[nf][r] + bias[o];
        }
    }
}

extern "C" void kernel_launch(void* const* d_in, const int* in_sizes, int n_in,
                              void* d_out, int out_size, void* d_ws, size_t ws_size,
                              hipStream_t stream) {
    const float* x    = (const float*)d_in[0];
    const float* flow = (const float*)d_in[1];
    const float* addf = (const float*)d_in[2];
    const float* w1   = (const float*)d_in[3];
    const float* b1   = (const float*)d_in[4];
    const float* w2   = (const float*)d_in[5];
    const float* b2   = (const float*)d_in[6];
    const float* w3   = (const float*)d_in[7];
    const float* b3   = (const float*)d_in[8];
    const float* w4   = (const float*)d_in[9];
    const float* b4   = (const float*)d_in[10];
    const float* wgt  = (const float*)d_in[11];
    const float* bias = (const float*)d_in[12];
    float* out = (float*)d_out;
    float* ws = (float*)d_ws;

    float* zp    = ws;                               // 256 f32
    u16*  pool_t = (u16*)(ws + 256);                 // 1,474,560 u16
    u16*  c1     = pool_t + 1474560;                 // 589,824 u16
    u16*  c2     = c1 + 589824;                      // 589,824 u16
    u16*  c3     = c1;                               // alias (c1 dead after conv2)
    float* a4    = (float*)(c2 + 589824);            // 1,990,656 f32
    u16*  wq1    = (u16*)(a4 + 1990656);             // 184,320 u16
    u16*  wq2    = wq1 + 184320;                     // 73,728
    u16*  wq3    = wq2 + 73728;                      // 73,728
    u16*  wq4    = wq3 + 73728;                      // 516,096
    u16*  wA     = wq4 + 516096;                     // 196,608 (fp16)
    u16*  xg     = wA + 196608;                      // 9,437,184 (fp16)

    fused_prep_kernel      <<<4081, 256, 0, stream>>>(w1, w2, w3, w4, wgt, zp, wq1, wq2, wq3, wq4, wA);
    fused_trans_pool_kernel<<<7488, 256, 0, stream>>>(x, flow, addf, xg, pool_t);

    conv_ks<160, 12, 23, 34, 45, true><<<dim3(144, 1, 2), 1024, 0, stream>>>(pool_t, wq1, b1, c1, zp);
    conv_ks<64,  5,  10, 14, 18, true><<<dim3(144, 1, 2), 1024, 0, stream>>>(c1, wq2, b2, c2, zp);
    conv_ks<64,  5,  10, 14, 18, true><<<dim3(144, 1, 2), 1024, 0, stream>>>(c2, wq3, b3, c3, zp);
    conv_mfma<64, 432, 448, false><<<dim3(144, 7, 2), 256, 0, stream>>>(c3, wq4, b4, a4, zp);

    deform_mfma<<<dim3(576, 2), 512, 0, stream>>>(xg, flow, a4, wA, bias, out);
}